// Round 1
// baseline (854.996 us; speedup 1.0000x reference)
//
#include <hip/hip_runtime.h>
#include <hip/hip_bf16.h>

// ---------------------------------------------------------------------------
// Compile-time construction of the 28x8 DWT composition matrix M:
//   y[k] = sum_j M[k][j] * patch[j],  k = [aa(7), ad(7), dd(7), da(7)]
// exactly matching pywt dwt mode='symmetric' applied twice (n=8 then n=7).
// ---------------------------------------------------------------------------
struct M28x8 { float m[28][8]; };

constexpr double DLO[8] = {-0.010597401784997278, 0.032883011666982945,
                            0.030841381835986965, -0.18703481171888114,
                           -0.02798376941698385,   0.6308807679295904,
                            0.7148465705525415,    0.23037781330885523};
constexpr double DHI[8] = {-0.23037781330885523,   0.7148465705525415,
                           -0.6308807679295904,   -0.02798376941698385,
                            0.18703481171888114,   0.030841381835986965,
                           -0.032883011666982945, -0.010597401784997278};

constexpr void dwt_c(const double* x, int n, double* lo, double* hi) {
    int out_len = (n + 7) / 2;
    for (int i = 0; i < out_len; ++i) {
        double a = 0.0, d = 0.0;
        for (int j = 0; j < 8; ++j) {
            int q = 2 * i + j - 6;
            if (q < 0) q = -q - 1;
            if (q >= n) q = 2 * n - 1 - q;
            a += DLO[7 - j] * x[q];
            d += DHI[7 - j] * x[q];
        }
        lo[i] = a; hi[i] = d;
    }
}

constexpr M28x8 build_M() {
    M28x8 R{};
    for (int j = 0; j < 8; ++j) {
        double x[8] = {0,0,0,0,0,0,0,0};
        x[j] = 1.0;
        double cA[7] = {}, cD[7] = {};
        dwt_c(x, 8, cA, cD);
        double aa[7] = {}, ad[7] = {}, da[7] = {}, dd[7] = {};
        dwt_c(cA, 7, aa, ad);
        dwt_c(cD, 7, da, dd);
        for (int i = 0; i < 7; ++i) {
            R.m[i][j]      = (float)aa[i];
            R.m[7 + i][j]  = (float)ad[i];
            R.m[14 + i][j] = (float)dd[i];   // dd before da in concat
            R.m[21 + i][j] = (float)da[i];
        }
    }
    return R;
}

__constant__ M28x8 g_M = build_M();

// ---------------------------------------------------------------------------
// Wfold[o][c*8+j] = sum_k W[o, c*28+k] * M[k][j]   -> 128*24 = 3072 floats
// ---------------------------------------------------------------------------
__global__ void wfold_kernel(const float* __restrict__ W, float* __restrict__ Wf) {
    int t = blockIdx.x * blockDim.x + threadIdx.x;
    if (t >= 128 * 24) return;
    int o = t / 24;
    int cj = t - o * 24;
    int c = cj >> 3;
    int j = cj & 7;
    const float* wr = W + o * 84 + c * 28;
    float acc = 0.f;
#pragma unroll
    for (int k = 0; k < 28; ++k) acc += wr[k] * g_M.m[k][j];
    Wf[t] = acc;
}

// ---------------------------------------------------------------------------
// Main kernel.
//   out[b, v*1024 + p, o] = sum_{c,j} Wfold[o][c*8+j] * x[b,c,min(4p+j,4095),v]
// Block = (b, 16-p tile). LDS slab x[b,:,t0:t0+68,:] stored [c][v][t].
// Each thread owns 4 consecutive o (96 weights in VGPRs).
// Restructured vs prior version:
//   * v is the outer loop; the two pl phases (grp, grp+8) are unrolled inside
//     it -> all ds_read / store offsets are compile-time immediates off two
//     pointers bumped once per v (no per-iter shifts / 64-bit muls).
//   * 8 independent FMA chains + 12 independent ds_read_b128 per v-iter give
//     the scheduler intra-wave overlap of LDS latency and VALU.
//   * __launch_bounds__(256,3): 3 waves/SIMD (12 waves/CU) instead of 2 —
//     VGPR cap ~168, est. live ~140, LDS 3 blocks/CU * 20.4 KB = 61 KB. OK.
// ---------------------------------------------------------------------------
#define PT   16              // p values per block
#define TT   (4 * PT + 4)    // 68 t values
#define SLAB (3 * 25 * TT)   // 5100 floats = 20.4 KB LDS

__global__ __launch_bounds__(256, 3) void wave_kernel(const float* __restrict__ x,
                                                      const float* __restrict__ Wf,
                                                      float* __restrict__ out) {
    __shared__ float s_x[SLAB];
    const int tile = blockIdx.x;       // 0..63
    const int b    = blockIdx.y;       // 0..31
    const int t0   = tile * (4 * PT);
    const int tid  = threadIdx.x;

    // stage global -> LDS (coalesced; runs of 1700 contiguous floats per ch)
    for (int lin = tid; lin < SLAB; lin += 256) {
        int v  = lin % 25;
        int r  = lin / 25;       // c*TT + tt
        int tt = r % TT;
        int c  = r / TT;
        int t  = t0 + tt;
        if (t > 4095) t = 4095;  // edge padding (PAD=4)
        s_x[(c * 25 + v) * TT + tt] = x[((b * 3 + c) * 4096 + t) * 25 + v];
    }

    const int og  = tid & 31;          // o-group: o = og*4
    const int grp = tid >> 5;          // 0..7 -> pl phases {grp, grp+8}
    const int o   = og << 2;

    // 4 rows of 24 folded weights in registers (L1-resident global loads)
    float wr[4][24];
#pragma unroll
    for (int m = 0; m < 4; ++m) {
        const float4* wp = (const float4*)(Wf + (o + m) * 24);
#pragma unroll
        for (int q = 0; q < 6; ++q) {
            float4 f = wp[q];
            wr[m][4 * q + 0] = f.x; wr[m][4 * q + 1] = f.y;
            wr[m][4 * q + 2] = f.z; wr[m][4 * q + 3] = f.w;
        }
    }

    __syncthreads();

    // Pointers for v=0; bumped by constants each v iteration.
    //   x read  (c,k): s_x + c*1700 + v*TT + 4*grp + 32*k  (+{0,4} for xa/xb)
    //   out (v, pl=grp+8k): out + ((b*25600 + tile*16)*128) + (v*1024+grp+8k)*128 + o
    const float* srow = s_x + 4 * grp;
    float* op = out + ((long)(b * 25600 + tile * PT)) * 128 + grp * 128 + o;

    for (int v = 0; v < 25; ++v) {
        float acc0[4] = {0.f, 0.f, 0.f, 0.f};
        float acc1[4] = {0.f, 0.f, 0.f, 0.f};
#pragma unroll
        for (int c = 0; c < 3; ++c) {
            const float4* r0 = (const float4*)(srow + c * (25 * TT));
            float4 xa0 = r0[0], xb0 = r0[1];   // pl = grp
            float4 xa1 = r0[8], xb1 = r0[9];   // pl = grp+8 (+32 floats)
#pragma unroll
            for (int m = 0; m < 4; ++m) {
                acc0[m] += wr[m][c*8+0]*xa0.x + wr[m][c*8+1]*xa0.y
                         + wr[m][c*8+2]*xa0.z + wr[m][c*8+3]*xa0.w
                         + wr[m][c*8+4]*xb0.x + wr[m][c*8+5]*xb0.y
                         + wr[m][c*8+6]*xb0.z + wr[m][c*8+7]*xb0.w;
                acc1[m] += wr[m][c*8+0]*xa1.x + wr[m][c*8+1]*xa1.y
                         + wr[m][c*8+2]*xa1.z + wr[m][c*8+3]*xa1.w
                         + wr[m][c*8+4]*xb1.x + wr[m][c*8+5]*xb1.y
                         + wr[m][c*8+6]*xb1.z + wr[m][c*8+7]*xb1.w;
            }
        }
        float4 s0 = {acc0[0], acc0[1], acc0[2], acc0[3]};
        float4 s1 = {acc1[0], acc1[1], acc1[2], acc1[3]};
        *(float4*)op            = s0;           // pl = grp
        *(float4*)(op + 1024)   = s1;           // pl = grp+8 (+8*128 floats)
        srow += TT;                              // v+1
        op   += 1024 * 128;                      // v+1
    }
}

extern "C" void kernel_launch(void* const* d_in, const int* in_sizes, int n_in,
                              void* d_out, int out_size, void* d_ws, size_t ws_size,
                              hipStream_t stream) {
    const float* x = (const float*)d_in[0];   // (32, 3, 4096, 25) fp32
    const float* W = (const float*)d_in[1];   // (128, 84) fp32
    float* out = (float*)d_out;               // (32, 25600, 128) fp32
    float* Wf  = (float*)d_ws;                // 3072 floats scratch

    hipLaunchKernelGGL(wfold_kernel, dim3(12), dim3(256), 0, stream, W, Wf);
    hipLaunchKernelGGL(wave_kernel, dim3(64, 32), dim3(256), 0, stream, x, Wf, out);
}

// Round 2
// 491.796 us; speedup vs baseline: 1.7385x; 1.7385x over previous
//
#include <hip/hip_runtime.h>
#include <hip/hip_bf16.h>

// ---------------------------------------------------------------------------
// Compile-time construction of the 28x8 DWT composition matrix M:
//   y[k] = sum_j M[k][j] * patch[j],  k = [aa(7), ad(7), dd(7), da(7)]
// exactly matching pywt dwt mode='symmetric' applied twice (n=8 then n=7).
// ---------------------------------------------------------------------------
struct M28x8 { float m[28][8]; };

constexpr double DLO[8] = {-0.010597401784997278, 0.032883011666982945,
                            0.030841381835986965, -0.18703481171888114,
                           -0.02798376941698385,   0.6308807679295904,
                            0.7148465705525415,    0.23037781330885523};
constexpr double DHI[8] = {-0.23037781330885523,   0.7148465705525415,
                           -0.6308807679295904,   -0.02798376941698385,
                            0.18703481171888114,   0.030841381835986965,
                           -0.032883011666982945, -0.010597401784997278};

constexpr void dwt_c(const double* x, int n, double* lo, double* hi) {
    int out_len = (n + 7) / 2;
    for (int i = 0; i < out_len; ++i) {
        double a = 0.0, d = 0.0;
        for (int j = 0; j < 8; ++j) {
            int q = 2 * i + j - 6;
            if (q < 0) q = -q - 1;
            if (q >= n) q = 2 * n - 1 - q;
            a += DLO[7 - j] * x[q];
            d += DHI[7 - j] * x[q];
        }
        lo[i] = a; hi[i] = d;
    }
}

constexpr M28x8 build_M() {
    M28x8 R{};
    for (int j = 0; j < 8; ++j) {
        double x[8] = {0,0,0,0,0,0,0,0};
        x[j] = 1.0;
        double cA[7] = {}, cD[7] = {};
        dwt_c(x, 8, cA, cD);
        double aa[7] = {}, ad[7] = {}, da[7] = {}, dd[7] = {};
        dwt_c(cA, 7, aa, ad);
        dwt_c(cD, 7, da, dd);
        for (int i = 0; i < 7; ++i) {
            R.m[i][j]      = (float)aa[i];
            R.m[7 + i][j]  = (float)ad[i];
            R.m[14 + i][j] = (float)dd[i];   // dd before da in concat
            R.m[21 + i][j] = (float)da[i];
        }
    }
    return R;
}

__constant__ M28x8 g_M = build_M();

// ---------------------------------------------------------------------------
// Wfold[o][c*8+j] = sum_k W[o, c*28+k] * M[k][j]   -> 128*24 = 3072 floats
// ---------------------------------------------------------------------------
__global__ void wfold_kernel(const float* __restrict__ W, float* __restrict__ Wf) {
    int t = blockIdx.x * blockDim.x + threadIdx.x;
    if (t >= 128 * 24) return;
    int o = t / 24;
    int cj = t - o * 24;
    int c = cj >> 3;
    int j = cj & 7;
    const float* wr = W + o * 84 + c * 28;
    float acc = 0.f;
#pragma unroll
    for (int k = 0; k < 28; ++k) acc += wr[k] * g_M.m[k][j];
    Wf[t] = acc;
}

// ---------------------------------------------------------------------------
// Main kernel.
//   out[b, v*1024 + p, o] = sum_{c,j} Wfold[o][c*8+j] * x[b,c,min(4p+j,4095),v]
// Block = (b, 16-p tile). LDS slab x[b,:,t0:t0+68,:] stored [c][v][t].
//
// Occupancy-first layout (round-2):
//   * each thread owns TWO o values (wr[2][24] = 48 regs, not 96) ->
//     peak live regs ~100, fits __launch_bounds__(256,4) cap of 128 with no
//     spill (round-1 spilled at cap 168 with the 96-reg weight array:
//     VGPR=84 + 1.28 GB scratch FETCH).
//   * og = tid&63: one full wave covers o=0..127 -> 64-lane float2 store is
//     one contiguous 512 B segment; ds_reads are wave-UNIFORM broadcasts.
//   * grp = tid>>6 (4 streams); per v each stream does pl = grp+4k, k=0..3,
//     fully unrolled so every LDS offset is a compile-time immediate off a
//     single per-v pointer (no runtime-indexed arrays -> no scratch).
//   * 4 waves/SIMD (16 waves/CU); LDS 4 x 20.4 KB = 81.6 KB/CU.
// ---------------------------------------------------------------------------
#define PT   16              // p values per block
#define TT   (4 * PT + 4)    // 68 t values
#define SLAB (3 * 25 * TT)   // 5100 floats = 20.4 KB LDS

__global__ __launch_bounds__(256, 4) void wave_kernel(const float* __restrict__ x,
                                                      const float* __restrict__ Wf,
                                                      float* __restrict__ out) {
    __shared__ float s_x[SLAB];
    const int tile = blockIdx.x;       // 0..63
    const int b    = blockIdx.y;       // 0..31
    const int t0   = tile * (4 * PT);
    const int tid  = threadIdx.x;

    // stage global -> LDS (coalesced; runs of 1700 contiguous floats per ch)
    for (int lin = tid; lin < SLAB; lin += 256) {
        int v  = lin % 25;
        int r  = lin / 25;       // c*TT + tt
        int tt = r % TT;
        int c  = r / TT;
        int t  = t0 + tt;
        if (t > 4095) t = 4095;  // edge padding (PAD=4)
        s_x[(c * 25 + v) * TT + tt] = x[((b * 3 + c) * 4096 + t) * 25 + v];
    }

    const int og  = tid & 63;          // o = og*2 : wave covers o = 0..127
    const int grp = tid >> 6;          // 0..3 -> pl phases {grp+4k}
    const int o   = og << 1;

    // 2 rows of 24 folded weights in registers (48 contiguous floats)
    float wr[2][24];
    {
        const float4* wp = (const float4*)(Wf + o * 24);
#pragma unroll
        for (int m = 0; m < 2; ++m) {
#pragma unroll
            for (int q = 0; q < 6; ++q) {
                float4 f = wp[m * 6 + q];
                wr[m][4 * q + 0] = f.x; wr[m][4 * q + 1] = f.y;
                wr[m][4 * q + 2] = f.z; wr[m][4 * q + 3] = f.w;
            }
        }
    }

    __syncthreads();

    // Per-v pointers; all inner offsets are compile-time immediates.
    //   LDS read (c,k): srow + c*1700 + 16*k + {0..7}
    //   store  (k):     op + 512*k   (pl = grp+4k -> +4*128 floats per k)
    const float* srow = s_x + 4 * grp;
    float* op = out + ((long)(b * 25600 + tile * PT)) * 128 + grp * 128 + o;

    for (int v = 0; v < 25; ++v) {
#pragma unroll
        for (int k = 0; k < 4; ++k) {
            const float* sk = srow + 16 * k;
            float acc0 = 0.f, acc1 = 0.f;
#pragma unroll
            for (int c = 0; c < 3; ++c) {
                const float4* r0 = (const float4*)(sk + c * (25 * TT));
                float4 xa = r0[0];
                float4 xb = r0[1];
                acc0 += wr[0][c*8+0]*xa.x + wr[0][c*8+1]*xa.y
                      + wr[0][c*8+2]*xa.z + wr[0][c*8+3]*xa.w
                      + wr[0][c*8+4]*xb.x + wr[0][c*8+5]*xb.y
                      + wr[0][c*8+6]*xb.z + wr[0][c*8+7]*xb.w;
                acc1 += wr[1][c*8+0]*xa.x + wr[1][c*8+1]*xa.y
                      + wr[1][c*8+2]*xa.z + wr[1][c*8+3]*xa.w
                      + wr[1][c*8+4]*xb.x + wr[1][c*8+5]*xb.y
                      + wr[1][c*8+6]*xb.z + wr[1][c*8+7]*xb.w;
            }
            float2 st = {acc0, acc1};
            *(float2*)(op + 512 * k) = st;
        }
        srow += TT;                 // v+1
        op   += 1024 * 128;         // v+1
    }
}

extern "C" void kernel_launch(void* const* d_in, const int* in_sizes, int n_in,
                              void* d_out, int out_size, void* d_ws, size_t ws_size,
                              hipStream_t stream) {
    const float* x = (const float*)d_in[0];   // (32, 3, 4096, 25) fp32
    const float* W = (const float*)d_in[1];   // (128, 84) fp32
    float* out = (float*)d_out;               // (32, 25600, 128) fp32
    float* Wf  = (float*)d_ws;                // 3072 floats scratch

    hipLaunchKernelGGL(wfold_kernel, dim3(12), dim3(256), 0, stream, W, Wf);
    hipLaunchKernelGGL(wave_kernel, dim3(64, 32), dim3(256), 0, stream, x, Wf, out);
}